// Round 10
// baseline (387.935 us; speedup 1.0000x reference)
//
#include <hip/hip_runtime.h>
#include <math.h>

#define SEQ  1024
#define DM   1024
#define NHD  8
#define DQKD 64
#define DVD  128
#define QKD  512
#define VD   1024
#define NB   2

__device__ __forceinline__ float softcap(float t) {
    return 15.0f * tanhf(t * (1.0f / 15.0f));
}

// ---------------- gates: i_pre/f_pre = softcap(x @ W^T + b), layout [b,h,t] ----------------
__global__ __launch_bounds__(256) void gates_kernel(
    const float* __restrict__ x,
    const float* __restrict__ Wi, const float* __restrict__ bi,
    const float* __restrict__ Wf, const float* __restrict__ bf,
    float* __restrict__ ipre, float* __restrict__ fpre) {
    int wid = threadIdx.x >> 6, lane = threadIdx.x & 63;
    int row = blockIdx.x * 4 + wid;          // 0..2047 = b*SEQ + t
    int b = row >> 10, t = row & 1023;
    const float* xr = x + (size_t)row * DM;
    float ai[NHD] = {}, af[NHD] = {};
    for (int d = lane; d < DM; d += 64) {
        float xv = xr[d];
#pragma unroll
        for (int h = 0; h < NHD; ++h) {
            ai[h] = fmaf(xv, Wi[h * DM + d], ai[h]);
            af[h] = fmaf(xv, Wf[h * DM + d], af[h]);
        }
    }
#pragma unroll
    for (int h = 0; h < NHD; ++h) {
        for (int off = 32; off > 0; off >>= 1) {
            ai[h] += __shfl_xor(ai[h], off);
            af[h] += __shfl_xor(af[h], off);
        }
    }
    if (lane == 0) {
#pragma unroll
        for (int h = 0; h < NHD; ++h) {
            ipre[((b * NHD + h) << 10) + t] = softcap(ai[h] + bi[h]);
            fpre[((b * NHD + h) << 10) + t] = softcap(af[h] + bf[h]);
        }
    }
}

// ---------------- per-(b,h) scans: cumF prefix-sum, prefix-max, suffix-max ----------------
__global__ __launch_bounds__(1024) void scan_kernel(
    const float* __restrict__ ipre, const float* __restrict__ fpre,
    float* __restrict__ gv, float* __restrict__ Mrow,
    float* __restrict__ sufg, float* __restrict__ expnegm) {
    __shared__ float sb[1024];
    int t = threadIdx.x, bh = blockIdx.x;
    int base = bh << 10;
    float f = fpre[base + t];
    sb[t] = f; __syncthreads();
    for (int off = 1; off < 1024; off <<= 1) {
        float v = sb[t];
        if (t >= off) v += sb[t - off];
        __syncthreads();
        sb[t] = v; __syncthreads();
    }
    float cumF = sb[t];
    float g = ipre[base + t] - cumF;
    gv[base + t] = g;
    __syncthreads();
    sb[t] = g; __syncthreads();
    for (int off = 1; off < 1024; off <<= 1) {
        float v = sb[t];
        if (t >= off) v = fmaxf(v, sb[t - off]);
        __syncthreads();
        sb[t] = v; __syncthreads();
    }
    float Mt = fmaxf(0.0f, sb[t]);      // include initial-state path (m0 = 0)
    Mrow[base + t] = Mt;
    expnegm[base + t] = expf(-(cumF + Mt));   // exp(-m_t)
    __syncthreads();
    sb[t] = g; __syncthreads();
    for (int off = 1; off < 1024; off <<= 1) {
        float v = sb[t];
        if (t + off < 1024) v = fmaxf(v, sb[t + off]);
        __syncthreads();
        sb[t] = v; __syncthreads();
    }
    sufg[base + t] = sb[t];
}

// ---------------- fused q/k/v/o projection GEMM: C = x @ W^T (NT), fp32 tiled ----------------
#define BM 64
#define BN 64
#define BKK 16
__global__ __launch_bounds__(256) void proj_gemm_kernel(
    const float* __restrict__ x,
    const float* __restrict__ Wq, const float* __restrict__ Wk,
    const float* __restrict__ Wv, const float* __restrict__ Wog,
    float* __restrict__ qb, float* __restrict__ kb,
    float* __restrict__ vb, float* __restrict__ ob) {
    __shared__ __align__(16) float As[BKK][BM + 4];
    __shared__ __align__(16) float Bs[BKK][BN + 4];
    int bx = blockIdx.x;                 // 0..47: 8 q-tiles, 8 k-tiles, 16 v-tiles, 16 o-tiles
    const float* W; float* C; int N; int col0;
    if (bx < 8)        { W = Wq;  C = qb; N = QKD; col0 = bx * BN; }
    else if (bx < 16)  { W = Wk;  C = kb; N = QKD; col0 = (bx - 8) * BN; }
    else if (bx < 32)  { W = Wv;  C = vb; N = VD;  col0 = (bx - 16) * BN; }
    else               { W = Wog; C = ob; N = VD;  col0 = (bx - 32) * BN; }
    int tid = threadIdx.x;
    int row0 = blockIdx.y * BM;
    int tx = tid & 15, ty = tid >> 4;
    int lr = tid >> 2, lc = tid & 3;
    const float* Ap = x + (size_t)(row0 + lr) * DM + lc * 4;
    const float* Bp = W + (size_t)(col0 + lr) * DM + lc * 4;
    float acc[4][4] = {};
    for (int k0 = 0; k0 < DM; k0 += BKK) {
        float4 a4 = *(const float4*)(Ap + k0);
        float4 b4 = *(const float4*)(Bp + k0);
        As[lc * 4 + 0][lr] = a4.x; As[lc * 4 + 1][lr] = a4.y;
        As[lc * 4 + 2][lr] = a4.z; As[lc * 4 + 3][lr] = a4.w;
        Bs[lc * 4 + 0][lr] = b4.x; Bs[lc * 4 + 1][lr] = b4.y;
        Bs[lc * 4 + 2][lr] = b4.z; Bs[lc * 4 + 3][lr] = b4.w;
        __syncthreads();
#pragma unroll
        for (int kk = 0; kk < BKK; ++kk) {
            float4 av = *(const float4*)(&As[kk][ty * 4]);
            float4 bv = *(const float4*)(&Bs[kk][tx * 4]);
            float ar[4] = {av.x, av.y, av.z, av.w};
            float br[4] = {bv.x, bv.y, bv.z, bv.w};
#pragma unroll
            for (int i = 0; i < 4; ++i)
#pragma unroll
                for (int j = 0; j < 4; ++j)
                    acc[i][j] = fmaf(ar[i], br[j], acc[i][j]);
        }
        __syncthreads();
    }
#pragma unroll
    for (int i = 0; i < 4; ++i) {
        float4 o4 = {acc[i][0], acc[i][1], acc[i][2], acc[i][3]};
        *(float4*)(C + (size_t)(row0 + ty * 4 + i) * N + col0 + tx * 4) = o4;
    }
}

// ---------------- generic NT GEMM for the output projection ----------------
__global__ __launch_bounds__(256) void gemm_nt_kernel(
    const float* __restrict__ A, const float* __restrict__ Bm,
    float* __restrict__ C, int N, int K) {
    __shared__ __align__(16) float As[BKK][BM + 4];
    __shared__ __align__(16) float Bs[BKK][BN + 4];
    int tid = threadIdx.x;
    int row0 = blockIdx.y * BM, col0 = blockIdx.x * BN;
    int tx = tid & 15, ty = tid >> 4;
    int lr = tid >> 2, lc = tid & 3;
    const float* Ap = A + (size_t)(row0 + lr) * K + lc * 4;
    const float* Bp = Bm + (size_t)(col0 + lr) * K + lc * 4;
    float acc[4][4] = {};
    for (int k0 = 0; k0 < K; k0 += BKK) {
        float4 a4 = *(const float4*)(Ap + k0);
        float4 b4 = *(const float4*)(Bp + k0);
        As[lc * 4 + 0][lr] = a4.x; As[lc * 4 + 1][lr] = a4.y;
        As[lc * 4 + 2][lr] = a4.z; As[lc * 4 + 3][lr] = a4.w;
        Bs[lc * 4 + 0][lr] = b4.x; Bs[lc * 4 + 1][lr] = b4.y;
        Bs[lc * 4 + 2][lr] = b4.z; Bs[lc * 4 + 3][lr] = b4.w;
        __syncthreads();
#pragma unroll
        for (int kk = 0; kk < BKK; ++kk) {
            float4 av = *(const float4*)(&As[kk][ty * 4]);
            float4 bv = *(const float4*)(&Bs[kk][tx * 4]);
            float ar[4] = {av.x, av.y, av.z, av.w};
            float br[4] = {bv.x, bv.y, bv.z, bv.w};
#pragma unroll
            for (int i = 0; i < 4; ++i)
#pragma unroll
                for (int j = 0; j < 4; ++j)
                    acc[i][j] = fmaf(ar[i], br[j], acc[i][j]);
        }
        __syncthreads();
    }
#pragma unroll
    for (int i = 0; i < 4; ++i) {
        float4 o4 = {acc[i][0], acc[i][1], acc[i][2], acc[i][3]};
        *(float4*)(C + (size_t)(row0 + ty * 4 + i) * N + col0 + tx * 4) = o4;
    }
}

// ---------------- windowed causal "attention" replacing the scan ----------------
// h_t = (sum_j w_{t,j} * (qs_t . k_j) * v_j) / denom,  w_{t,j} = exp(g_j - M_t)
__global__ __launch_bounds__(256) void attn_kernel(
    const float* __restrict__ q, const float* __restrict__ k,
    const float* __restrict__ v, const float* __restrict__ gv,
    const float* __restrict__ Mrow, const float* __restrict__ sufg,
    const float* __restrict__ expnegm, float* __restrict__ hbuf) {
    int wid = threadIdx.x >> 6, lane = threadIdx.x & 63;
    int bh = blockIdx.x;                 // 0..15
    int t = blockIdx.y * 4 + wid;        // 0..1023
    int b = bh >> 3, h = bh & 7;
    int base = bh << 10;
    float Mt = Mrow[base + t];
    float qs = q[(size_t)(b * SEQ + t) * QKD + h * DQKD + lane] * 0.125f;
    float num0 = 0.0f, num1 = 0.0f, qn = 0.0f;
    for (int j = 0; j <= t; ++j) {
        if ((j & 15) == 0) {
            if (sufg[base + j] - Mt < -60.0f) break;   // all remaining weights < e^-60
        }
        float kj = k[(size_t)(b * SEQ + j) * QKD + h * DQKD + lane];
        float s = qs * kj;
#pragma unroll
        for (int off = 32; off > 0; off >>= 1) s += __shfl_xor(s, off);
        float w = expf(gv[base + j] - Mt);
        float p = w * s;
        qn += p;
        const float* vr = v + (size_t)(b * SEQ + j) * VD + h * DVD;
        num0 = fmaf(p, vr[lane], num0);
        num1 = fmaf(p, vr[lane + 64], num1);
    }
    float denom = fmaxf(fabsf(qn), expnegm[base + t]) + 1e-6f;
    float* hr = hbuf + (size_t)(b * SEQ + t) * VD + h * DVD;
    hr[lane] = num0 / denom;
    hr[lane + 64] = num1 / denom;
}

// ---------------- layernorm over NH*DV + sigmoid output gate ----------------
__global__ __launch_bounds__(256) void ln_gate_kernel(
    const float* __restrict__ hbuf, const float* __restrict__ o,
    const float* __restrict__ lnw, const float* __restrict__ lnb,
    float* __restrict__ hout) {
    int row = blockIdx.x, tid = threadIdx.x;
    float4 hv = ((const float4*)(hbuf + (size_t)row * VD))[tid];
    float s1 = hv.x + hv.y + hv.z + hv.w;
    float s2 = hv.x * hv.x + hv.y * hv.y + hv.z * hv.z + hv.w * hv.w;
    for (int off = 32; off > 0; off >>= 1) {
        s1 += __shfl_xor(s1, off);
        s2 += __shfl_xor(s2, off);
    }
    __shared__ float w1[4], w2[4];
    int wid = tid >> 6, lane = tid & 63;
    if (lane == 0) { w1[wid] = s1; w2[wid] = s2; }
    __syncthreads();
    s1 = w1[0] + w1[1] + w1[2] + w1[3];
    s2 = w2[0] + w2[1] + w2[2] + w2[3];
    float mean = s1 * (1.0f / 1024.0f);
    float var = s2 * (1.0f / 1024.0f) - mean * mean;
    float rs = rsqrtf(var + 1e-6f);
    float4 ov = ((const float4*)(o + (size_t)row * VD))[tid];
    float4 wv = ((const float4*)lnw)[tid];
    float4 bv = ((const float4*)lnb)[tid];
    float4 out;
    out.x = (1.0f / (1.0f + expf(-ov.x))) * ((hv.x - mean) * rs * wv.x + bv.x);
    out.y = (1.0f / (1.0f + expf(-ov.y))) * ((hv.y - mean) * rs * wv.y + bv.y);
    out.z = (1.0f / (1.0f + expf(-ov.z))) * ((hv.z - mean) * rs * wv.z + bv.z);
    out.w = (1.0f / (1.0f + expf(-ov.w))) * ((hv.w - mean) * rs * wv.w + bv.w);
    ((float4*)(hout + (size_t)row * VD))[tid] = out;
}

extern "C" void kernel_launch(void* const* d_in, const int* in_sizes, int n_in,
                              void* d_out, int out_size, void* d_ws, size_t ws_size,
                              hipStream_t stream) {
    const float* x    = (const float*)d_in[0];
    const float* Wq   = (const float*)d_in[1];
    const float* Wk   = (const float*)d_in[2];
    const float* Wv   = (const float*)d_in[3];
    const float* Wog  = (const float*)d_in[4];
    const float* Wi   = (const float*)d_in[5];
    const float* bi   = (const float*)d_in[6];
    const float* Wf   = (const float*)d_in[7];
    const float* bf   = (const float*)d_in[8];
    const float* lnw  = (const float*)d_in[9];
    const float* lnb  = (const float*)d_in[10];
    const float* Wout = (const float*)d_in[11];
    float* out = (float*)d_out;

    float* ws = (float*)d_ws;
    const size_t BH   = (size_t)NB * NHD * SEQ;      // 16384
    const size_t ROWS = (size_t)NB * SEQ;            // 2048
    // Minimal workspace (~25.6 MB) to rule out ws_size overflow as a failure mode.
    float* ipre = ws;                 // 6 x [16,1024]
    float* fpre = ipre + BH;
    float* gv   = fpre + BH;
    float* Mrow = gv + BH;
    float* sufg = Mrow + BH;
    float* enm  = sufg + BH;
    float* qb   = enm + BH;           // [2048, 512]  4.2 MB
    float* kb   = qb + ROWS * QKD;    // [2048, 512]  4.2 MB
    float* vb   = kb + ROWS * QKD;    // [2048, 1024] 8.4 MB
    float* ob   = vb + ROWS * VD;     // [2048, 1024] 8.4 MB
    // Aliases (stream-ordered, race-free):
    float* hb   = out;                // attn fully writes d_out; LN reads it; final GEMM overwrites
    float* hg   = qb;                 // qb+kb (8.4 MB) dead after attn; hg written by LN after attn

    gates_kernel<<<512, 256, 0, stream>>>(x, Wi, bi, Wf, bf, ipre, fpre);
    scan_kernel<<<16, 1024, 0, stream>>>(ipre, fpre, gv, Mrow, sufg, enm);
    proj_gemm_kernel<<<dim3(48, ROWS / BM), 256, 0, stream>>>(x, Wq, Wk, Wv, Wog, qb, kb, vb, ob);
    attn_kernel<<<dim3(16, SEQ / 4), 256, 0, stream>>>(qb, kb, vb, gv, Mrow, sufg, enm, hb);
    ln_gate_kernel<<<ROWS, 256, 0, stream>>>(hb, ob, lnw, lnb, hg);
    gemm_nt_kernel<<<dim3(DM / BN, ROWS / BM), 256, 0, stream>>>(hg, Wout, out, DM, VD);
}

// Round 11
// 278.740 us; speedup vs baseline: 1.3917x; 1.3917x over previous
//
#include <hip/hip_runtime.h>
#include <math.h>

#define SEQ  1024
#define DM   1024
#define NHD  8
#define DQKD 64
#define DVD  128
#define QKD  512
#define VD   1024
#define NB   2
#define VOC  2048   // vob row stride: v(1024) | o(1024)

typedef __attribute__((ext_vector_type(8))) short bf16x8;
typedef __attribute__((ext_vector_type(4))) float f32x4;

__device__ __forceinline__ float softcap(float t) {
    return 15.0f * tanhf(t * (1.0f / 15.0f));
}

__device__ __forceinline__ unsigned short f2bf(float f) {
    union { float f; unsigned u; } v; v.f = f;
    unsigned r = v.u + 0x7FFFu + ((v.u >> 16) & 1u);   // round-to-nearest-even
    return (unsigned short)(r >> 16);
}

// ---------------- fp32 -> bf16 convert, 4 elems/thread ----------------
__global__ __launch_bounds__(256) void cvt_kernel(const float* __restrict__ src,
                                                  unsigned short* __restrict__ dst, int n4) {
    int i = blockIdx.x * 256 + threadIdx.x;
    if (i < n4) {
        float4 v = ((const float4*)src)[i];
        ushort4 o;
        o.x = f2bf(v.x); o.y = f2bf(v.y); o.z = f2bf(v.z); o.w = f2bf(v.w);
        ((ushort4*)dst)[i] = o;
    }
}

// ---------------- gates: i_pre/f_pre = softcap(x @ W^T + b), layout [b,h,t] ----------------
__global__ __launch_bounds__(256) void gates_kernel(
    const float* __restrict__ x,
    const float* __restrict__ Wi, const float* __restrict__ bi,
    const float* __restrict__ Wf, const float* __restrict__ bf,
    float* __restrict__ ipre, float* __restrict__ fpre) {
    int wid = threadIdx.x >> 6, lane = threadIdx.x & 63;
    int row = blockIdx.x * 4 + wid;          // 0..2047 = b*SEQ + t
    int b = row >> 10, t = row & 1023;
    const float* xr = x + (size_t)row * DM;
    float ai[NHD] = {}, af[NHD] = {};
    for (int d = lane; d < DM; d += 64) {
        float xv = xr[d];
#pragma unroll
        for (int h = 0; h < NHD; ++h) {
            ai[h] = fmaf(xv, Wi[h * DM + d], ai[h]);
            af[h] = fmaf(xv, Wf[h * DM + d], af[h]);
        }
    }
#pragma unroll
    for (int h = 0; h < NHD; ++h) {
        for (int off = 32; off > 0; off >>= 1) {
            ai[h] += __shfl_xor(ai[h], off);
            af[h] += __shfl_xor(af[h], off);
        }
    }
    if (lane == 0) {
#pragma unroll
        for (int h = 0; h < NHD; ++h) {
            ipre[((b * NHD + h) << 10) + t] = softcap(ai[h] + bi[h]);
            fpre[((b * NHD + h) << 10) + t] = softcap(af[h] + bf[h]);
        }
    }
}

// ---------------- per-(b,h) scans: cumF prefix-sum, prefix-max, suffix-max ----------------
__global__ __launch_bounds__(1024) void scan_kernel(
    const float* __restrict__ ipre, const float* __restrict__ fpre,
    float* __restrict__ gv, float* __restrict__ Mrow,
    float* __restrict__ sufg, float* __restrict__ expnegm) {
    __shared__ float sb[1024];
    int t = threadIdx.x, bh = blockIdx.x;
    int base = bh << 10;
    float f = fpre[base + t];
    sb[t] = f; __syncthreads();
    for (int off = 1; off < 1024; off <<= 1) {
        float v = sb[t];
        if (t >= off) v += sb[t - off];
        __syncthreads();
        sb[t] = v; __syncthreads();
    }
    float cumF = sb[t];
    float g = ipre[base + t] - cumF;
    gv[base + t] = g;
    __syncthreads();
    sb[t] = g; __syncthreads();
    for (int off = 1; off < 1024; off <<= 1) {
        float v = sb[t];
        if (t >= off) v = fmaxf(v, sb[t - off]);
        __syncthreads();
        sb[t] = v; __syncthreads();
    }
    float Mt = fmaxf(0.0f, sb[t]);      // include initial-state path (m0 = 0)
    Mrow[base + t] = Mt;
    expnegm[base + t] = expf(-(cumF + Mt));   // exp(-m_t)
    __syncthreads();
    sb[t] = g; __syncthreads();
    for (int off = 1; off < 1024; off <<= 1) {
        float v = sb[t];
        if (t + off < 1024) v = fmaxf(v, sb[t + off]);
        __syncthreads();
        sb[t] = v; __syncthreads();
    }
    sufg[base + t] = sb[t];
}

// ---------------- q/k projection GEMM: fp32 (conditioning-critical path) ----------------
#define BM 64
#define BN 64
#define BKK 16
__global__ __launch_bounds__(256) void qk_gemm_kernel(
    const float* __restrict__ x,
    const float* __restrict__ Wq, const float* __restrict__ Wk,
    float* __restrict__ qb, float* __restrict__ kb) {
    __shared__ __align__(16) float As[BKK][BM + 4];
    __shared__ __align__(16) float Bs[BKK][BN + 4];
    int bx = blockIdx.x;                 // 0..15: 8 q-tiles, 8 k-tiles
    const float* W; float* C; int col0;
    if (bx < 8) { W = Wq; C = qb; col0 = bx * BN; }
    else        { W = Wk; C = kb; col0 = (bx - 8) * BN; }
    int tid = threadIdx.x;
    int row0 = blockIdx.y * BM;
    int tx = tid & 15, ty = tid >> 4;
    int lr = tid >> 2, lc = tid & 3;
    const float* Ap = x + (size_t)(row0 + lr) * DM + lc * 4;
    const float* Bp = W + (size_t)(col0 + lr) * DM + lc * 4;
    float acc[4][4] = {};
    for (int k0 = 0; k0 < DM; k0 += BKK) {
        float4 a4 = *(const float4*)(Ap + k0);
        float4 b4 = *(const float4*)(Bp + k0);
        As[lc * 4 + 0][lr] = a4.x; As[lc * 4 + 1][lr] = a4.y;
        As[lc * 4 + 2][lr] = a4.z; As[lc * 4 + 3][lr] = a4.w;
        Bs[lc * 4 + 0][lr] = b4.x; Bs[lc * 4 + 1][lr] = b4.y;
        Bs[lc * 4 + 2][lr] = b4.z; Bs[lc * 4 + 3][lr] = b4.w;
        __syncthreads();
#pragma unroll
        for (int kk = 0; kk < BKK; ++kk) {
            float4 av = *(const float4*)(&As[kk][ty * 4]);
            float4 bv = *(const float4*)(&Bs[kk][tx * 4]);
            float ar[4] = {av.x, av.y, av.z, av.w};
            float br[4] = {bv.x, bv.y, bv.z, bv.w};
#pragma unroll
            for (int i = 0; i < 4; ++i)
#pragma unroll
                for (int j = 0; j < 4; ++j)
                    acc[i][j] = fmaf(ar[i], br[j], acc[i][j]);
        }
        __syncthreads();
    }
#pragma unroll
    for (int i = 0; i < 4; ++i) {
        float4 o4 = {acc[i][0], acc[i][1], acc[i][2], acc[i][3]};
        *(float4*)(C + (size_t)(row0 + ty * 4 + i) * QKD + col0 + tx * 4) = o4;
    }
}

// ---------------- bf16 MFMA NT GEMM: C[M][ldc] = A[M][K] . B[ldc-rows][K]^T ----------------
// m97 structure: 128x128 tile, BK=32, 4 waves (2x2), global_load_lds w=16, single LDS buf.
__global__ __launch_bounds__(256) void mfma_nt_kernel(
    const unsigned short* __restrict__ A, const unsigned short* __restrict__ B,
    float* __restrict__ C, int ldc, int K) {
    __shared__ __align__(16) unsigned short As[128 * 32];
    __shared__ __align__(16) unsigned short Bs[128 * 32];
    int tid = threadIdx.x;
    int w = tid >> 6, l = tid & 63;
    int wr = w >> 1, wc = w & 1;
    int r0 = blockIdx.y * 128, c0 = blockIdx.x * 128;
    f32x4 acc[4][4] = {};
    for (int k0 = 0; k0 < K; k0 += 32) {
        // stage A,B tiles: per call a wave loads 64 lanes x 16B = 16 rows x 32 bf16
#pragma unroll
        for (int it = 0; it < 2; ++it) {
            const unsigned short* ga = A + (size_t)(r0 + it * 64 + w * 16 + (l >> 2)) * K + k0 + ((l & 3) << 3);
            __builtin_amdgcn_global_load_lds(
                (const __attribute__((address_space(1))) unsigned int*)ga,
                (__attribute__((address_space(3))) unsigned int*)&As[(it * 64 + w * 16) * 32],
                16, 0, 0);
            const unsigned short* gb = B + (size_t)(c0 + it * 64 + w * 16 + (l >> 2)) * K + k0 + ((l & 3) << 3);
            __builtin_amdgcn_global_load_lds(
                (const __attribute__((address_space(1))) unsigned int*)gb,
                (__attribute__((address_space(3))) unsigned int*)&Bs[(it * 64 + w * 16) * 32],
                16, 0, 0);
        }
        __syncthreads();   // drains vmcnt before any wave reads LDS
        bf16x8 af[4], bfr[4];
#pragma unroll
        for (int mi = 0; mi < 4; ++mi)
            af[mi] = *(const bf16x8*)&As[(wr * 64 + mi * 16 + (l & 15)) * 32 + ((l >> 4) << 3)];
#pragma unroll
        for (int ni = 0; ni < 4; ++ni)
            bfr[ni] = *(const bf16x8*)&Bs[(wc * 64 + ni * 16 + (l & 15)) * 32 + ((l >> 4) << 3)];
#pragma unroll
        for (int mi = 0; mi < 4; ++mi)
#pragma unroll
            for (int ni = 0; ni < 4; ++ni)
                acc[mi][ni] = __builtin_amdgcn_mfma_f32_16x16x32_bf16(af[mi], bfr[ni], acc[mi][ni], 0, 0, 0);
        __syncthreads();   // protect LDS from next stage
    }
    // C/D layout (m89/m91): col = lane&15, row = (lane>>4)*4 + reg
#pragma unroll
    for (int mi = 0; mi < 4; ++mi) {
#pragma unroll
        for (int ni = 0; ni < 4; ++ni) {
            int row = r0 + wr * 64 + mi * 16 + ((l >> 4) << 2);
            int col = c0 + wc * 64 + ni * 16 + (l & 15);
            float* cp = C + (size_t)row * ldc + col;
#pragma unroll
            for (int j = 0; j < 4; ++j) cp[(size_t)j * ldc] = acc[mi][ni][j];
        }
    }
}

// ---------------- windowed causal "attention" replacing the scan ----------------
// h_t = (sum_j w_{t,j} * (qs_t . k_j) * v_j) / denom,  w_{t,j} = exp(g_j - M_t)
__global__ __launch_bounds__(256) void attn_kernel(
    const float* __restrict__ q, const float* __restrict__ k,
    const float* __restrict__ vob, const float* __restrict__ gv,
    const float* __restrict__ Mrow, const float* __restrict__ sufg,
    const float* __restrict__ expnegm, float* __restrict__ hbuf) {
    int wid = threadIdx.x >> 6, lane = threadIdx.x & 63;
    int bh = blockIdx.x;                 // 0..15
    int t = blockIdx.y * 4 + wid;        // 0..1023
    int b = bh >> 3, h = bh & 7;
    int base = bh << 10;
    float Mt = Mrow[base + t];
    float qs = q[(size_t)(b * SEQ + t) * QKD + h * DQKD + lane] * 0.125f;
    float num0 = 0.0f, num1 = 0.0f, qn = 0.0f;
    for (int j = 0; j <= t; ++j) {
        if ((j & 15) == 0) {
            if (sufg[base + j] - Mt < -60.0f) break;   // all remaining weights < e^-60
        }
        float kj = k[(size_t)(b * SEQ + j) * QKD + h * DQKD + lane];
        float s = qs * kj;
#pragma unroll
        for (int off = 32; off > 0; off >>= 1) s += __shfl_xor(s, off);
        float w = expf(gv[base + j] - Mt);
        float p = w * s;
        qn += p;
        const float* vr = vob + (size_t)(b * SEQ + j) * VOC + h * DVD;
        num0 = fmaf(p, vr[lane], num0);
        num1 = fmaf(p, vr[lane + 64], num1);
    }
    float denom = fmaxf(fabsf(qn), expnegm[base + t]) + 1e-6f;
    float* hr = hbuf + (size_t)(b * SEQ + t) * VD + h * DVD;
    hr[lane] = num0 / denom;
    hr[lane + 64] = num1 / denom;
}

// ---------------- layernorm over NH*DV + sigmoid output gate, emit bf16 ----------------
__global__ __launch_bounds__(256) void ln_gate_kernel(
    const float* __restrict__ hbuf, const float* __restrict__ vob,
    const float* __restrict__ lnw, const float* __restrict__ lnb,
    unsigned short* __restrict__ hgbf) {
    int row = blockIdx.x, tid = threadIdx.x;
    float4 hv = ((const float4*)(hbuf + (size_t)row * VD))[tid];
    float s1 = hv.x + hv.y + hv.z + hv.w;
    float s2 = hv.x * hv.x + hv.y * hv.y + hv.z * hv.z + hv.w * hv.w;
    for (int off = 32; off > 0; off >>= 1) {
        s1 += __shfl_xor(s1, off);
        s2 += __shfl_xor(s2, off);
    }
    __shared__ float w1[4], w2[4];
    int wid = tid >> 6, lane = tid & 63;
    if (lane == 0) { w1[wid] = s1; w2[wid] = s2; }
    __syncthreads();
    s1 = w1[0] + w1[1] + w1[2] + w1[3];
    s2 = w2[0] + w2[1] + w2[2] + w2[3];
    float mean = s1 * (1.0f / 1024.0f);
    float var = s2 * (1.0f / 1024.0f) - mean * mean;
    float rs = rsqrtf(var + 1e-6f);
    float4 ov = ((const float4*)(vob + (size_t)row * VOC + VD))[tid];   // o-gate half
    float4 wv = ((const float4*)lnw)[tid];
    float4 bv = ((const float4*)lnb)[tid];
    float ox = (1.0f / (1.0f + expf(-ov.x))) * ((hv.x - mean) * rs * wv.x + bv.x);
    float oy = (1.0f / (1.0f + expf(-ov.y))) * ((hv.y - mean) * rs * wv.y + bv.y);
    float oz = (1.0f / (1.0f + expf(-ov.z))) * ((hv.z - mean) * rs * wv.z + bv.z);
    float ow = (1.0f / (1.0f + expf(-ov.w))) * ((hv.w - mean) * rs * wv.w + bv.w);
    ushort4 o4;
    o4.x = f2bf(ox); o4.y = f2bf(oy); o4.z = f2bf(oz); o4.w = f2bf(ow);
    ((ushort4*)(hgbf + (size_t)row * VD))[tid] = o4;
}

extern "C" void kernel_launch(void* const* d_in, const int* in_sizes, int n_in,
                              void* d_out, int out_size, void* d_ws, size_t ws_size,
                              hipStream_t stream) {
    const float* x    = (const float*)d_in[0];
    const float* Wq   = (const float*)d_in[1];
    const float* Wk   = (const float*)d_in[2];
    const float* Wv   = (const float*)d_in[3];
    const float* Wog  = (const float*)d_in[4];
    const float* Wi   = (const float*)d_in[5];
    const float* bi   = (const float*)d_in[6];
    const float* Wf   = (const float*)d_in[7];
    const float* bf   = (const float*)d_in[8];
    const float* lnw  = (const float*)d_in[9];
    const float* lnb  = (const float*)d_in[10];
    const float* Wout = (const float*)d_in[11];
    float* out = (float*)d_out;

    float* ws = (float*)d_ws;
    const size_t BH   = (size_t)NB * NHD * SEQ;      // 16384
    const size_t ROWS = (size_t)NB * SEQ;            // 2048
    // Workspace: IDENTICAL 25.6 MB footprint to the round-10 PASSING layout.
    float* ipre = ws;                 // 6 x [16,1024]
    float* fpre = ipre + BH;
    float* gv   = fpre + BH;
    float* Mrow = gv + BH;
    float* sufg = Mrow + BH;
    float* enm  = sufg + BH;
    float* qb   = enm + BH;           // [2048, 512] fp32, 4.2 MB  (slot A)
    float* kb   = qb + ROWS * QKD;    // [2048, 512] fp32, 4.2 MB  (slot B)
    float* vob  = kb + ROWS * QKD;    // [2048, 2048] fp32, 16.8 MB (v | o)
    // Stream-ordered slot reuse (each alias's producer runs after the slot's last reader):
    unsigned short* xbf   = (unsigned short*)qb;  // slot A: x bf16, dead after vo-mfma; qk-gemm then writes qb
    unsigned short* Wvobf = (unsigned short*)kb;  // slot B: Wv|Wog bf16, dead after vo-mfma; qk-gemm then writes kb
    unsigned short* hgbf  = (unsigned short*)qb;  // slot A again: qb dead after attn; ln_gate writes after attn
    unsigned short* Wobf  = (unsigned short*)kb;  // slot B again: kb dead after attn; cvt runs after attn
    float* hb = out;                  // attn fully writes d_out; ln reads; out-mfma overwrites

    // Phase 1: bf16 conversions into slots A/B
    cvt_kernel<<<2048, 256, 0, stream>>>(x, xbf, (int)(ROWS * DM / 4));
    cvt_kernel<<<1024, 256, 0, stream>>>(Wv,  Wvobf,                    VD * DM / 4);
    cvt_kernel<<<1024, 256, 0, stream>>>(Wog, Wvobf + (size_t)VD * DM,  VD * DM / 4);
    gates_kernel<<<512, 256, 0, stream>>>(x, Wi, bi, Wf, bf, ipre, fpre);
    scan_kernel<<<16, 1024, 0, stream>>>(ipre, fpre, gv, Mrow, sufg, enm);
    // Phase 2: v|o = xbf . Wvobf^T  [2048, 2048]  (last reader of slots A/B)
    mfma_nt_kernel<<<dim3(VOC / 128, ROWS / 128), 256, 0, stream>>>(xbf, Wvobf, vob, VOC, DM);
    // Phase 3: q,k in fp32 (overwrites slots A/B)
    qk_gemm_kernel<<<dim3(16, ROWS / BM), 256, 0, stream>>>(x, Wq, Wk, qb, kb);
    // Phase 4: windowed attention (last reader of qb,kb)
    attn_kernel<<<dim3(16, SEQ / 4), 256, 0, stream>>>(qb, kb, vob, gv, Mrow, sufg, enm, hb);
    // Phase 5: Wout -> bf16 into slot B; LN+gate -> bf16 into slot A
    cvt_kernel<<<1024, 256, 0, stream>>>(Wout, Wobf, DM * VD / 4);
    ln_gate_kernel<<<ROWS, 256, 0, stream>>>(hb, vob, lnw, lnb, hgbf);
    // Phase 6: out = hgbf . Wobf^T  [2048, 1024]
    mfma_nt_kernel<<<dim3(DM / 128, ROWS / 128), 256, 0, stream>>>(hgbf, Wobf, out, DM, VD);
}